// Round 5
// baseline (152.709 us; speedup 1.0000x reference)
//
#include <hip/hip_runtime.h>
#include <hip/hip_bf16.h>
#include <cstdint>
#include <cstddef>

// ---------------- types ----------------
typedef float    f32x4   __attribute__((ext_vector_type(4)));
typedef float    float4v __attribute__((ext_vector_type(4)));
typedef short    short8  __attribute__((ext_vector_type(8)));
typedef __bf16   bf16x8  __attribute__((ext_vector_type(8)));
typedef unsigned short ushort4v __attribute__((ext_vector_type(4)));

// ---------------- problem constants ----------------
constexpr int NB   = 4;       // batch
constexpr int TT   = 2048;    // sequence
constexpr int DD   = 1024;    // model dim (= head dim, single head)
constexpr int MTOT = NB * TT; // 8192 tokens

// ---------------- helpers ----------------
__device__ __forceinline__ unsigned short f2bf(float f) {
  union { float f; uint32_t u; } v; v.f = f;
  uint32_t u = v.u;
  uint32_t r = u + 0x7fffu + ((u >> 16) & 1u); // RNE
  return (unsigned short)(r >> 16);
}
__device__ __forceinline__ float bf2f(unsigned short h) {
  union { uint32_t u; float f; } v; v.u = ((uint32_t)h) << 16;
  return v.f;
}

// ---------------- fused fp32 -> bf16 convert ----------------
__global__ void cvt_all(const float* __restrict__ x,  const float* __restrict__ wq,
                        const float* __restrict__ wk, const float* __restrict__ wv,
                        unsigned short* __restrict__ xb,  unsigned short* __restrict__ wqb,
                        unsigned short* __restrict__ wkb, unsigned short* __restrict__ wvb) {
  const int NX = (MTOT * DD) / 4;
  const int NW = (DD * DD) / 4;
  int i = blockIdx.x * blockDim.x + threadIdx.x;
  const float* s; unsigned short* d; int off;
  if (i < NX)               { s = x;  d = xb;  off = i; }
  else if (i < NX + NW)     { s = wq; d = wqb; off = i - NX; }
  else if (i < NX + 2 * NW) { s = wk; d = wkb; off = i - NX - NW; }
  else if (i < NX + 3 * NW) { s = wv; d = wvb; off = i - NX - 2 * NW; }
  else return;
  float4v v = *(const float4v*)(s + (size_t)off * 4);
  ushort4v o;
  o[0] = f2bf(v[0]); o[1] = f2bf(v[1]); o[2] = f2bf(v[2]); o[3] = f2bf(v[3]);
  *(ushort4v*)(d + (size_t)off * 4) = o;
}

// ============================================================================
// 128x128 / BK=32 / ring-4 deep-pipelined bt-GEMM core.
// LDS ring: 4 slots x (A[128][32] + B[128][32]) bf16 = 4 x 16 KB = 64 KB.
// Swizzle (rule-21 involution pair, verified write<->read):
//   LDS (row r, 16B-chunk pos p) holds global (row r, chunk p ^ ((r>>1)&3)).
//   stage: lane l -> row (l>>2), src chunk (l&3)^((l>>3)&3)   [per-lane const]
//   read:  frag row l&15, chunk c=l>>4 at pos c^((l>>1)&3)    [conflict-min]
// Pipeline: stage tile t+2 during tile t; trailing s_waitcnt vmcnt(4) leaves
// tile t+2 in flight and guarantees tile t+1 (issued 2 phases ago) landed.
// vmcnt never 0 in the main loop (T4); per-phase barrier pair + setprio (T3/T5).
// ============================================================================
__device__ __forceinline__ void stage_tile32(const unsigned short* gA,
                                             const unsigned short* gB,
                                             int lda, int ldb,
                                             unsigned short* slot,
                                             int l, int w, int srcswz) {
  #pragma unroll
  for (int i = 0; i < 2; ++i) {
    const int rbase = i * 64 + w * 16;                        // wave-uniform
    const unsigned short* srca = gA + (size_t)(rbase + (l >> 2)) * lda + srcswz;
    __builtin_amdgcn_global_load_lds(
        (const __attribute__((address_space(1))) void*)srca,
        (__attribute__((address_space(3))) void*)(slot + rbase * 32), 16, 0, 0);
  }
  #pragma unroll
  for (int i = 0; i < 2; ++i) {
    const int rbase = i * 64 + w * 16;
    const unsigned short* srcb = gB + (size_t)(rbase + (l >> 2)) * ldb + srcswz;
    __builtin_amdgcn_global_load_lds(
        (const __attribute__((address_space(1))) void*)srcb,
        (__attribute__((address_space(3))) void*)(slot + 4096 + rbase * 32), 16, 0, 0);
  }
}

__device__ __forceinline__ void gemm_core32(
    const unsigned short* __restrict__ A, const unsigned short* __restrict__ Bm,
    int lda, int ldb, int nt, unsigned short* smem, f32x4 acc[4][4])
{
  const int t = threadIdx.x;
  const int w = t >> 6, l = t & 63;
  const int wr = (w >> 1) * 64, wc = (w & 1) * 64;
  const int lrow = l & 15;
  const int rdswz  = (((l >> 4) ^ ((l >> 1) & 3))) * 8;   // halfwords
  const int srcswz = (((l & 3) ^ ((l >> 3) & 3))) * 8;    // halfwords

  // prologue: stage tiles 0 and 1 (8 loads/thread)
  stage_tile32(A,      Bm,      lda, ldb, smem,        l, w, srcswz);
  stage_tile32(A + 32, Bm + 32, lda, ldb, smem + 8192, l, w, srcswz);
  asm volatile("s_waitcnt vmcnt(4)" ::: "memory");   // tile 0 landed
  __builtin_amdgcn_s_barrier();
  __builtin_amdgcn_sched_barrier(0);

  for (int tt = 0; tt < nt; ++tt) {
    unsigned short* slot = smem + (tt & 3) * 8192;
    const unsigned short* Ab = slot;
    const unsigned short* Bb = slot + 4096;

    bf16x8 av[4], bv[4];
    #pragma unroll
    for (int m = 0; m < 4; ++m)
      av[m] = *(const bf16x8*)(Ab + (wr + m * 16 + lrow) * 32 + rdswz);
    #pragma unroll
    for (int n = 0; n < 4; ++n)
      bv[n] = *(const bf16x8*)(Bb + (wc + n * 16 + lrow) * 32 + rdswz);

    if (tt + 2 < nt)
      stage_tile32(A + (size_t)(tt + 2) * 32, Bm + (size_t)(tt + 2) * 32,
                   lda, ldb, smem + ((tt + 2) & 3) * 8192, l, w, srcswz);

    __builtin_amdgcn_s_barrier();
    asm volatile("s_waitcnt lgkmcnt(0)" ::: "memory");
    __builtin_amdgcn_sched_barrier(0);

    __builtin_amdgcn_s_setprio(1);
    #pragma unroll
    for (int m = 0; m < 4; ++m)
      #pragma unroll
      for (int n = 0; n < 4; ++n)
        acc[m][n] = __builtin_amdgcn_mfma_f32_16x16x32_bf16(av[m], bv[n], acc[m][n], 0, 0, 0);
    __builtin_amdgcn_s_setprio(0);
    __builtin_amdgcn_sched_barrier(0);

    if (tt + 1 < nt) {
      if (tt + 2 < nt) asm volatile("s_waitcnt vmcnt(4)" ::: "memory"); // tile t+1 ready
      else             asm volatile("s_waitcnt vmcnt(0)" ::: "memory"); // last prefetch
    }
    __builtin_amdgcn_s_barrier();
    __builtin_amdgcn_sched_barrier(0);
  }
}

// ---------------- QKV projection ----------------
__global__ __launch_bounds__(256, 2) void qkv_gemm(
    const unsigned short* __restrict__ xb,
    const unsigned short* __restrict__ wqb,
    const unsigned short* __restrict__ wkb,
    const unsigned short* __restrict__ wvb,
    unsigned short* __restrict__ qb,
    unsigned short* __restrict__ kb,
    unsigned short* __restrict__ vtb)
{
  __shared__ __align__(16) unsigned short smem[32768];   // 64 KB ring / epi

  const int id   = blockIdx.x;                  // 1536 blocks, %8==0
  const int work = (id & 7) * 192 + (id >> 3);  // XCD-contiguous chunks
  const int which = work / 512;
  const int rem   = work - which * 512;
  const int row0  = (rem >> 3) * 128;           // token tile
  const int col0  = (rem & 7) * 128;            // out-dim tile

  const unsigned short* W = (which == 0) ? wqb : (which == 1) ? wkb : wvb;

  f32x4 acc[4][4];
  #pragma unroll
  for (int m = 0; m < 4; ++m)
    #pragma unroll
    for (int n = 0; n < 4; ++n)
      acc[m][n] = (f32x4){0.f, 0.f, 0.f, 0.f};

  gemm_core32(xb + (size_t)row0 * DD, W + (size_t)col0 * DD, DD, DD, DD / 32, smem, acc);

  const int t = threadIdx.x, w = t >> 6, l = t & 63;
  const int wr = (w >> 1) * 64, wc = (w & 1) * 64;

  unsigned short* Ts = smem;  // [128][136]
  #pragma unroll
  for (int m = 0; m < 4; ++m)
    #pragma unroll
    for (int n = 0; n < 4; ++n)
      #pragma unroll
      for (int r = 0; r < 4; ++r) {
        int rr = wr + m * 16 + (l >> 4) * 4 + r;   // token-local 0..127
        int cc = wc + n * 16 + (l & 15);           // odim-local  0..127
        unsigned short hv = f2bf(acc[m][n][r]);
        if (which == 2) Ts[cc * 136 + rr] = hv;
        else            Ts[rr * 136 + cc] = hv;
      }
  __syncthreads();

  if (which == 2) {
    const int bb = row0 >> 11, t0 = row0 & 2047;
    #pragma unroll
    for (int i = 0; i < 8; ++i) {
      int idx = i * 256 + t;
      int ol  = idx >> 4;            // odim-local row 0..127
      int c16 = (idx & 15) << 3;     // token chunk
      short8 v = *(const short8*)(Ts + ol * 136 + c16);
      *(short8*)(vtb + ((size_t)bb * DD + col0 + ol) * TT + t0 + c16) = v;
    }
  } else {
    unsigned short* dst = (which == 0) ? qb : kb;
    #pragma unroll
    for (int i = 0; i < 8; ++i) {
      int idx = i * 256 + t;
      int rl  = idx >> 4;            // token-local row 0..127
      int c16 = (idx & 15) << 3;     // odim chunk
      short8 v = *(const short8*)(Ts + rl * 136 + c16);
      *(short8*)(dst + (size_t)(row0 + rl) * DD + col0 + c16) = v;
    }
  }
}

// ---------------- QK^T (causal, scaled, bf16 logits) ----------------
__global__ __launch_bounds__(256, 2) void qk_gemm(
    const unsigned short* __restrict__ qb,
    const unsigned short* __restrict__ kb,
    unsigned short* __restrict__ Pb)
{
  __shared__ __align__(16) unsigned short smem[32768];

  const int id   = blockIdx.x;                 // 544 blocks, %8==0
  const int work = (id & 7) * 68 + (id >> 3);
  const int b    = work / 136;
  const int i    = work - b * 136;
  int row = (int)((sqrtf(8.0f * (float)i + 1.0f) - 1.0f) * 0.5f);
  while ((row + 1) * (row + 2) / 2 <= i) ++row;
  while (row * (row + 1) / 2 > i) --row;
  const int col  = i - row * (row + 1) / 2;
  const int row0 = row * 128, col0 = col * 128;

  const unsigned short* A = qb + (size_t)b * TT * DD + (size_t)row0 * DD;
  const unsigned short* K = kb + (size_t)b * TT * DD + (size_t)col0 * DD;

  f32x4 acc[4][4];
  #pragma unroll
  for (int m = 0; m < 4; ++m)
    #pragma unroll
    for (int n = 0; n < 4; ++n)
      acc[m][n] = (f32x4){0.f, 0.f, 0.f, 0.f};

  gemm_core32(A, K, DD, DD, DD / 32, smem, acc);

  const float scale = 0.03125f;  // 1/sqrt(1024)
  const int t = threadIdx.x, w = t >> 6, l = t & 63;
  const int wr = (w >> 1) * 64, wc = (w & 1) * 64;
  unsigned short* Prow = Pb + (size_t)b * TT * TT;
  #pragma unroll
  for (int m = 0; m < 4; ++m)
    #pragma unroll
    for (int n = 0; n < 4; ++n)
      #pragma unroll
      for (int r = 0; r < 4; ++r) {
        int grow = row0 + wr + m * 16 + (l >> 4) * 4 + r;
        int gcol = col0 + wc + n * 16 + (l & 15);
        if (gcol <= grow)
          Prow[(size_t)grow * TT + gcol] = f2bf(acc[m][n][r] * scale);
      }
}

// ---------------- row softmax (single pass, vectorized, in place) ----------
__global__ __launch_bounds__(256) void softmax_kernel(unsigned short* __restrict__ Pb)
{
  const int q = blockIdx.x, b = blockIdx.y;
  unsigned short* row = Pb + ((size_t)b * TT + q) * TT;
  const int L    = q + 1;                  // valid length
  const int tend = ((q >> 7) + 1) << 7;    // PV reads [0, tend)
  const int t = threadIdx.x;
  const int c0 = t << 3;
  const bool has = c0 < tend;

  float f[8];
  float mx = -3.0e38f;
  if (has) {
    short8 v = *(const short8*)(row + c0);
    #pragma unroll
    for (int j = 0; j < 8; ++j) {
      float x = bf2f((unsigned short)v[j]);
      f[j] = (c0 + j < L) ? x : -3.0e38f;
      mx = fmaxf(mx, f[j]);
    }
  }
  #pragma unroll
  for (int o = 32; o > 0; o >>= 1) mx = fmaxf(mx, __shfl_down(mx, o));
  __shared__ float redm[4];
  if ((t & 63) == 0) redm[t >> 6] = mx;
  __syncthreads();
  mx = fmaxf(fmaxf(redm[0], redm[1]), fmaxf(redm[2], redm[3]));

  float e[8];
  float s = 0.f;
  if (has) {
    #pragma unroll
    for (int j = 0; j < 8; ++j) {
      e[j] = (c0 + j < L) ? __expf(f[j] - mx) : 0.0f;
      s += e[j];
    }
  }
  #pragma unroll
  for (int o = 32; o > 0; o >>= 1) s += __shfl_down(s, o);
  __shared__ float reds[4];
  if ((t & 63) == 0) reds[t >> 6] = s;
  __syncthreads();
  s = reds[0] + reds[1] + reds[2] + reds[3];
  const float inv = 1.0f / s;

  if (has) {
    short8 o8;
    #pragma unroll
    for (int j = 0; j < 8; ++j) o8[j] = (short)f2bf(e[j] * inv);
    *(short8*)(row + c0) = o8;
  }
}

// ---------------- PV: O = P * V (via vT, bt-GEMM), fp32 out ----------------
__global__ __launch_bounds__(256, 2) void pv_gemm(
    const unsigned short* __restrict__ Pb,
    const unsigned short* __restrict__ vtb,
    float* __restrict__ out)
{
  __shared__ __align__(16) unsigned short smem[32768];

  const int id   = blockIdx.x;                 // 512 blocks
  const int work = (id & 7) * 64 + (id >> 3);
  const int b    = work >> 7;
  const int rem  = work & 127;
  const int row0 = (rem >> 3) * 128;           // q tile
  const int col0 = (rem & 7) * 128;            // out-dim tile

  const unsigned short* A  = Pb  + (size_t)b * TT * TT + (size_t)row0 * TT;
  const unsigned short* Bm = vtb + (size_t)b * DD * TT + (size_t)col0 * TT;

  f32x4 acc[4][4];
  #pragma unroll
  for (int m = 0; m < 4; ++m)
    #pragma unroll
    for (int n = 0; n < 4; ++n)
      acc[m][n] = (f32x4){0.f, 0.f, 0.f, 0.f};

  gemm_core32(A, Bm, TT, TT, (row0 >> 5) + 4, smem, acc);

  const int t = threadIdx.x, w = t >> 6, l = t & 63;
  const int wr = (w >> 1) * 64, wc = (w & 1) * 64;
  #pragma unroll
  for (int m = 0; m < 4; ++m)
    #pragma unroll
    for (int n = 0; n < 4; ++n)
      #pragma unroll
      for (int r = 0; r < 4; ++r) {
        int grow = row0 + wr + m * 16 + (l >> 4) * 4 + r;
        int gcol = col0 + wc + n * 16 + (l & 15);
        out[((size_t)b * TT + grow) * DD + gcol] = acc[m][n][r];
      }
}

// ---------------- launch ----------------
extern "C" void kernel_launch(void* const* d_in, const int* in_sizes, int n_in,
                              void* d_out, int out_size, void* d_ws, size_t ws_size,
                              hipStream_t stream) {
  const float* x  = (const float*)d_in[0];
  const float* Wq = (const float*)d_in[1];
  const float* Wk = (const float*)d_in[2];
  const float* Wv = (const float*)d_in[3];
  float* out = (float*)d_out;

  unsigned short* ws  = (unsigned short*)d_ws;
  unsigned short* xb  = ws;                        // 8192*1024
  unsigned short* wqb = xb  + (size_t)MTOT * DD;   // 1024*1024
  unsigned short* wkb = wqb + (size_t)DD * DD;
  unsigned short* wvb = wkb + (size_t)DD * DD;
  unsigned short* qb  = wvb + (size_t)DD * DD;     // 8192*1024
  unsigned short* kb  = qb  + (size_t)MTOT * DD;   // 8192*1024
  unsigned short* vtb = kb  + (size_t)MTOT * DD;   // 4*1024*2048 (vT)
  unsigned short* Pb  = vtb + (size_t)MTOT * DD;   // 4*2048*2048

  {
    const int NX = (MTOT * DD) / 4, NW = (DD * DD) / 4;
    const int ntot = NX + 3 * NW;
    cvt_all<<<(ntot + 255) / 256, 256, 0, stream>>>(x, Wq, Wk, Wv, xb, wqb, wkb, wvb);
  }

  qkv_gemm<<<dim3(1536), 256, 0, stream>>>(xb, wqb, wkb, wvb, qb, kb, vtb);

  qk_gemm<<<dim3(544), 256, 0, stream>>>(qb, kb, Pb);

  softmax_kernel<<<dim3(TT, NB), 256, 0, stream>>>(Pb);

  pv_gemm<<<dim3(512), 256, 0, stream>>>(Pb, vtb, out);
}

// Round 6
// 148.708 us; speedup vs baseline: 1.0269x; 1.0269x over previous
//
#include <hip/hip_runtime.h>
#include <hip/hip_bf16.h>
#include <cstdint>
#include <cstddef>

// ---------------- types ----------------
typedef float    f32x4   __attribute__((ext_vector_type(4)));
typedef float    float4v __attribute__((ext_vector_type(4)));
typedef short    short8  __attribute__((ext_vector_type(8)));
typedef __bf16   bf16x8  __attribute__((ext_vector_type(8)));
typedef unsigned short ushort4v __attribute__((ext_vector_type(4)));

// ---------------- problem constants ----------------
constexpr int NB   = 4;       // batch
constexpr int TT   = 2048;    // sequence
constexpr int DD   = 1024;    // model dim (= head dim, single head)
constexpr int MTOT = NB * TT; // 8192 tokens

// ---------------- helpers ----------------
__device__ __forceinline__ unsigned short f2bf(float f) {
  union { float f; uint32_t u; } v; v.f = f;
  uint32_t u = v.u;
  uint32_t r = u + 0x7fffu + ((u >> 16) & 1u); // RNE
  return (unsigned short)(r >> 16);
}
__device__ __forceinline__ float bf2f(unsigned short h) {
  union { uint32_t u; float f; } v; v.u = ((uint32_t)h) << 16;
  return v.f;
}

// ---------------- fused fp32 -> bf16 convert ----------------
__global__ void cvt_all(const float* __restrict__ x,  const float* __restrict__ wq,
                        const float* __restrict__ wk, const float* __restrict__ wv,
                        unsigned short* __restrict__ xb,  unsigned short* __restrict__ wqb,
                        unsigned short* __restrict__ wkb, unsigned short* __restrict__ wvb) {
  const int NX = (MTOT * DD) / 4;
  const int NW = (DD * DD) / 4;
  int i = blockIdx.x * blockDim.x + threadIdx.x;
  const float* s; unsigned short* d; int off;
  if (i < NX)               { s = x;  d = xb;  off = i; }
  else if (i < NX + NW)     { s = wq; d = wqb; off = i - NX; }
  else if (i < NX + 2 * NW) { s = wk; d = wkb; off = i - NX - NW; }
  else if (i < NX + 3 * NW) { s = wv; d = wvb; off = i - NX - 2 * NW; }
  else return;
  float4v v = *(const float4v*)(s + (size_t)off * 4);
  ushort4v o;
  o[0] = f2bf(v[0]); o[1] = f2bf(v[1]); o[2] = f2bf(v[2]); o[3] = f2bf(v[3]);
  *(ushort4v*)(d + (size_t)off * 4) = o;
}

// ============================================================================
// QKV: 256x256 tile / BK=32 / ring-4 / 8 waves (512 thr).
// LDS ring: 4 slots x (A[256][32] + B[256][32]) bf16 = 4 x 32 KB = 128 KiB.
// Linear LDS (rows are 64 B -> natural 2-way bank alias only = free; no
// swizzle, global_load_lds dest linear). Waves 2M x 4N, per-wave out 128x64:
// 32 MFMA / 12 ds_read_b128 per tile per thread (ratio 2.67).
// Pipeline: stage tile t+2 during tile t; ONE barrier + ONE vmcnt(4) per tile
// (never drains; vmcnt(0) only for the last tile). Slot (t+2)&3 was last read
// in tile t-2; those reads completed (lgkmcnt 0 before their MFMAs) before
// barrier(t-1) <= barrier(t), and the stage is issued after barrier(t).
// ============================================================================
__device__ __forceinline__ void stage_ab32(const unsigned short* g, int ld,
                                           unsigned short* dst, int w, int l) {
  #pragma unroll
  for (int i = 0; i < 2; ++i) {
    const int rbase = (i * 8 + w) * 16;                       // wave-uniform
    const unsigned short* src = g + (size_t)(rbase + (l >> 2)) * ld + ((l & 3) << 3);
    __builtin_amdgcn_global_load_lds(
        (const __attribute__((address_space(1))) void*)src,
        (__attribute__((address_space(3))) void*)(dst + rbase * 32), 16, 0, 0);
  }
}

__global__ __launch_bounds__(512, 1) void qkv_gemm256(
    const unsigned short* __restrict__ xb,
    const unsigned short* __restrict__ wqb,
    const unsigned short* __restrict__ wkb,
    const unsigned short* __restrict__ wvb,
    unsigned short* __restrict__ qb,
    unsigned short* __restrict__ kb,
    unsigned short* __restrict__ vtb)
{
  __shared__ __align__(16) unsigned short smem[65536];   // 128 KiB

  const int id   = blockIdx.x;                  // 384 blocks, %8==0
  const int work = (id & 7) * 48 + (id >> 3);   // XCD-contiguous chunks
  const int which = work >> 7;                  // 0=Q,1=K,2=V
  const int rem   = work & 127;
  const int row0  = (rem >> 2) * 256;           // token tile
  const int col0  = (rem & 3) * 256;            // out-dim tile

  const unsigned short* Wt = (which == 0) ? wqb : (which == 1) ? wkb : wvb;
  const unsigned short* A  = xb + (size_t)row0 * DD;
  const unsigned short* B  = Wt + (size_t)col0 * DD;

  const int t = threadIdx.x;
  const int w = t >> 6, l = t & 63;
  const int wr = (w >> 2) * 128;                // wave-row base (0/128)
  const int wc = (w & 3) * 64;                  // wave-col base (0/64/128/192)
  const int lrow = l & 15, lk = (l >> 4) * 8;

  f32x4 acc[8][4];
  #pragma unroll
  for (int m = 0; m < 8; ++m)
    #pragma unroll
    for (int n = 0; n < 4; ++n)
      acc[m][n] = (f32x4){0.f, 0.f, 0.f, 0.f};

  constexpr int nt = DD / 32;   // 32 K-tiles

  // prologue: stage tiles 0 and 1 (8 loads/thread in flight)
  stage_ab32(A,      DD, smem,                 w, l);
  stage_ab32(B,      DD, smem + 8192,          w, l);
  stage_ab32(A + 32, DD, smem + 16384,         w, l);
  stage_ab32(B + 32, DD, smem + 16384 + 8192,  w, l);

  for (int tt = 0; tt < nt; ++tt) {
    if (tt + 1 < nt) asm volatile("s_waitcnt vmcnt(4)" ::: "memory"); // tile tt landed, tt+1 in flight
    else             asm volatile("s_waitcnt vmcnt(0)" ::: "memory"); // last tile
    __builtin_amdgcn_s_barrier();
    __builtin_amdgcn_sched_barrier(0);

    unsigned short* slot = smem + (tt & 3) * 16384;
    const unsigned short* Ab = slot;
    const unsigned short* Bb = slot + 8192;
    unsigned short* nslot = smem + ((tt + 2) & 3) * 16384;
    const bool pf = (tt + 2 < nt);

    // ---- sub-phase 0: B-frags + A-frags 0..3 | stage A(t+2) | 16 MFMA ----
    bf16x8 bv[4], av0[4];
    #pragma unroll
    for (int n = 0; n < 4; ++n)
      bv[n] = *(const bf16x8*)(Bb + (wc + n * 16 + lrow) * 32 + lk);
    #pragma unroll
    for (int m = 0; m < 4; ++m)
      av0[m] = *(const bf16x8*)(Ab + (wr + m * 16 + lrow) * 32 + lk);
    if (pf) stage_ab32(A + (size_t)(tt + 2) * 32, DD, nslot, w, l);
    asm volatile("s_waitcnt lgkmcnt(0)" ::: "memory");
    __builtin_amdgcn_sched_barrier(0);
    __builtin_amdgcn_s_setprio(1);
    #pragma unroll
    for (int m = 0; m < 4; ++m)
      #pragma unroll
      for (int n = 0; n < 4; ++n)
        acc[m][n] = __builtin_amdgcn_mfma_f32_16x16x32_bf16(av0[m], bv[n], acc[m][n], 0, 0, 0);
    __builtin_amdgcn_s_setprio(0);
    __builtin_amdgcn_sched_barrier(0);

    // ---- sub-phase 1: A-frags 4..7 | stage B(t+2) | 16 MFMA ----
    bf16x8 av1[4];
    #pragma unroll
    for (int m = 0; m < 4; ++m)
      av1[m] = *(const bf16x8*)(Ab + (wr + (m + 4) * 16 + lrow) * 32 + lk);
    if (pf) stage_ab32(B + (size_t)(tt + 2) * 32, DD, nslot + 8192, w, l);
    asm volatile("s_waitcnt lgkmcnt(0)" ::: "memory");
    __builtin_amdgcn_sched_barrier(0);
    __builtin_amdgcn_s_setprio(1);
    #pragma unroll
    for (int m = 0; m < 4; ++m)
      #pragma unroll
      for (int n = 0; n < 4; ++n)
        acc[m + 4][n] = __builtin_amdgcn_mfma_f32_16x16x32_bf16(av1[m], bv[n], acc[m + 4][n], 0, 0, 0);
    __builtin_amdgcn_s_setprio(0);
    __builtin_amdgcn_sched_barrier(0);
  }

  // ---- epilogue (proven in R4): LDS transpose -> coalesced 16B stores ----
  unsigned short* Ts = smem;               // [128][264]
  if (which != 2) {
    unsigned short* dst = (which == 0) ? qb : kb;
    const int halfsel = w >> 2;            // this wave's row-half
    #pragma unroll
    for (int h = 0; h < 2; ++h) {
      __syncthreads();
      if (halfsel == h) {
        #pragma unroll
        for (int m = 0; m < 8; ++m)
          #pragma unroll
          for (int n = 0; n < 4; ++n)
            #pragma unroll
            for (int r = 0; r < 4; ++r) {
              int rr = m * 16 + (l >> 4) * 4 + r;      // 0..127 within half
              int cc = wc + n * 16 + (l & 15);         // 0..255
              Ts[rr * 264 + cc] = f2bf(acc[m][n][r]);
            }
      }
      __syncthreads();
      #pragma unroll
      for (int i = 0; i < 8; ++i) {
        int idx = i * 512 + t;
        int rl  = idx >> 5;                // 0..127
        int c8  = (idx & 31) << 3;         // 0..248
        short8 v = *(const short8*)(Ts + rl * 264 + c8);
        *(short8*)(dst + (size_t)(row0 + h * 128 + rl) * DD + col0 + c8) = v;
      }
    }
  } else {
    const int bb = row0 >> 11, t0 = row0 & 2047;
    const int csel = (w >> 1) & 1;         // this wave's col-half
    #pragma unroll
    for (int h = 0; h < 2; ++h) {
      __syncthreads();
      if (csel == h) {
        #pragma unroll
        for (int m = 0; m < 8; ++m)
          #pragma unroll
          for (int n = 0; n < 4; ++n)
            #pragma unroll
            for (int r = 0; r < 4; ++r) {
              int rr  = wr + m * 16 + (l >> 4) * 4 + r;        // token 0..255
              int ccl = (wc - h * 128) + n * 16 + (l & 15);    // 0..127
              Ts[ccl * 264 + rr] = f2bf(acc[m][n][r]);
            }
      }
      __syncthreads();
      #pragma unroll
      for (int i = 0; i < 8; ++i) {
        int idx = i * 512 + t;
        int ol  = idx >> 5;                // odim-local 0..127
        int c8  = (idx & 31) << 3;         // token chunk 0..248
        short8 v = *(const short8*)(Ts + ol * 264 + c8);
        *(short8*)(vtb + ((size_t)bb * DD + col0 + h * 128 + ol) * TT + t0 + c8) = v;
      }
    }
  }
}

// ============================================================================
// 128x128 / BK=64 / dbuf / vmcnt(8) bt-GEMM core (round-3 proven) for qk / pv
// ============================================================================
__device__ __forceinline__ void stage_tile(const unsigned short* g0, int ld,
                                           unsigned short* lds, int l, int w,
                                           int srcswz) {
  #pragma unroll
  for (int it = 0; it < 4; ++it) {
    const int rbase = ((it << 2) + w) << 3;
    const unsigned short* src =
        g0 + (size_t)(rbase + (l >> 3)) * ld + srcswz;
    __builtin_amdgcn_global_load_lds(
        (const __attribute__((address_space(1))) void*)src,
        (__attribute__((address_space(3))) void*)(lds + rbase * 64),
        16, 0, 0);
  }
}

__device__ __forceinline__ void gemm_core(
    const unsigned short* __restrict__ A, const unsigned short* __restrict__ Bm,
    int lda, int ldb, int kbeg, int kend,
    unsigned short* smem, f32x4 acc[4][4])
{
  const int t = threadIdx.x;
  const int w = t >> 6, l = t & 63;
  const int wr = (w >> 1) * 64, wc = (w & 1) * 64;
  const int lrow = l & 15, lk = (l >> 4) * 8;
  const int swr    = (l & 7) << 3;
  const int srcswz = (((l & 7) ^ (l >> 3)) << 3);

  unsigned short* A0 = smem;
  unsigned short* B0 = smem + 8192;
  unsigned short* A1 = smem + 16384;
  unsigned short* B1 = smem + 24576;

  const int NT = (kend - kbeg) >> 6;

  stage_tile(A + kbeg, lda, A0, l, w, srcswz);
  stage_tile(Bm + kbeg, ldb, B0, l, w, srcswz);

  for (int tt = 0; tt < NT; ++tt) {
    unsigned short* Ac = (tt & 1) ? A1 : A0;
    unsigned short* Bc = (tt & 1) ? B1 : B0;
    if (tt + 1 < NT) {
      unsigned short* An = (tt & 1) ? A0 : A1;
      unsigned short* Bn = (tt & 1) ? B0 : B1;
      const int k1 = kbeg + ((tt + 1) << 6);
      stage_tile(A + k1, lda, An, l, w, srcswz);
      stage_tile(Bm + k1, ldb, Bn, l, w, srcswz);
      asm volatile("s_waitcnt vmcnt(8)" ::: "memory");
    } else {
      asm volatile("s_waitcnt vmcnt(0)" ::: "memory");
    }
    __builtin_amdgcn_s_barrier();
    __builtin_amdgcn_sched_barrier(0);

    #pragma unroll
    for (int kk = 0; kk < 64; kk += 32) {
      bf16x8 av[4], bv[4];
      #pragma unroll
      for (int m = 0; m < 4; ++m)
        av[m] = *(const bf16x8*)(Ac + (wr + m * 16 + lrow) * 64 + ((kk + lk) ^ swr));
      #pragma unroll
      for (int n = 0; n < 4; ++n)
        bv[n] = *(const bf16x8*)(Bc + (wc + n * 16 + lrow) * 64 + ((kk + lk) ^ swr));
      __builtin_amdgcn_s_setprio(1);
      #pragma unroll
      for (int m = 0; m < 4; ++m)
        #pragma unroll
        for (int n = 0; n < 4; ++n)
          acc[m][n] = __builtin_amdgcn_mfma_f32_16x16x32_bf16(av[m], bv[n], acc[m][n], 0, 0, 0);
      __builtin_amdgcn_s_setprio(0);
    }
    __builtin_amdgcn_sched_barrier(0);
    __builtin_amdgcn_s_barrier();
    __builtin_amdgcn_sched_barrier(0);
  }
}

// ---------------- QK^T (causal, scaled, bf16 logits) ----------------
__global__ __launch_bounds__(256, 2) void qk_gemm(
    const unsigned short* __restrict__ qb,
    const unsigned short* __restrict__ kb,
    unsigned short* __restrict__ Pb)
{
  __shared__ __align__(16) unsigned short smem[32768];

  const int id   = blockIdx.x;                 // 544 blocks, %8==0
  const int work = (id & 7) * 68 + (id >> 3);
  const int b    = work / 136;
  const int i    = work - b * 136;
  int row = (int)((sqrtf(8.0f * (float)i + 1.0f) - 1.0f) * 0.5f);
  while ((row + 1) * (row + 2) / 2 <= i) ++row;
  while (row * (row + 1) / 2 > i) --row;
  const int col  = i - row * (row + 1) / 2;
  const int row0 = row * 128, col0 = col * 128;

  const unsigned short* A = qb + (size_t)b * TT * DD + (size_t)row0 * DD;
  const unsigned short* K = kb + (size_t)b * TT * DD + (size_t)col0 * DD;

  f32x4 acc[4][4];
  #pragma unroll
  for (int m = 0; m < 4; ++m)
    #pragma unroll
    for (int n = 0; n < 4; ++n)
      acc[m][n] = (f32x4){0.f, 0.f, 0.f, 0.f};

  gemm_core(A, K, DD, DD, 0, DD, smem, acc);

  const float scale = 0.03125f;  // 1/sqrt(1024)
  const int t = threadIdx.x, w = t >> 6, l = t & 63;
  const int wr = (w >> 1) * 64, wc = (w & 1) * 64;
  unsigned short* Prow = Pb + (size_t)b * TT * TT;
  #pragma unroll
  for (int m = 0; m < 4; ++m)
    #pragma unroll
    for (int n = 0; n < 4; ++n)
      #pragma unroll
      for (int r = 0; r < 4; ++r) {
        int grow = row0 + wr + m * 16 + (l >> 4) * 4 + r;
        int gcol = col0 + wc + n * 16 + (l & 15);
        if (gcol <= grow)
          Prow[(size_t)grow * TT + gcol] = f2bf(acc[m][n][r] * scale);
      }
}

// ---------------- row softmax (single pass, vectorized, in place) ----------
__global__ __launch_bounds__(256) void softmax_kernel(unsigned short* __restrict__ Pb)
{
  const int q = blockIdx.x, b = blockIdx.y;
  unsigned short* row = Pb + ((size_t)b * TT + q) * TT;
  const int L    = q + 1;                  // valid length
  const int tend = ((q >> 7) + 1) << 7;    // PV reads [0, tend)
  const int t = threadIdx.x;
  const int c0 = t << 3;
  const bool has = c0 < tend;

  float f[8];
  float mx = -3.0e38f;
  if (has) {
    short8 v = *(const short8*)(row + c0);
    #pragma unroll
    for (int j = 0; j < 8; ++j) {
      float x = bf2f((unsigned short)v[j]);
      f[j] = (c0 + j < L) ? x : -3.0e38f;
      mx = fmaxf(mx, f[j]);
    }
  }
  #pragma unroll
  for (int o = 32; o > 0; o >>= 1) mx = fmaxf(mx, __shfl_down(mx, o));
  __shared__ float redm[4];
  if ((t & 63) == 0) redm[t >> 6] = mx;
  __syncthreads();
  mx = fmaxf(fmaxf(redm[0], redm[1]), fmaxf(redm[2], redm[3]));

  float e[8];
  float s = 0.f;
  if (has) {
    #pragma unroll
    for (int j = 0; j < 8; ++j) {
      e[j] = (c0 + j < L) ? __expf(f[j] - mx) : 0.0f;
      s += e[j];
    }
  }
  #pragma unroll
  for (int o = 32; o > 0; o >>= 1) s += __shfl_down(s, o);
  __shared__ float reds[4];
  if ((t & 63) == 0) reds[t >> 6] = s;
  __syncthreads();
  s = reds[0] + reds[1] + reds[2] + reds[3];
  const float inv = 1.0f / s;

  if (has) {
    short8 o8;
    #pragma unroll
    for (int j = 0; j < 8; ++j) o8[j] = (short)f2bf(e[j] * inv);
    *(short8*)(row + c0) = o8;
  }
}

// ---------------- PV: O = P * V (via vT, bt-GEMM), fp32 out ----------------
__global__ __launch_bounds__(256, 2) void pv_gemm(
    const unsigned short* __restrict__ Pb,
    const unsigned short* __restrict__ vtb,
    float* __restrict__ out)
{
  __shared__ __align__(16) unsigned short smem[32768];

  const int id   = blockIdx.x;                 // 512 blocks
  const int work = (id & 7) * 64 + (id >> 3);
  const int b    = work >> 7;
  const int rem  = work & 127;
  const int row0 = (rem >> 3) * 128;           // q tile
  const int col0 = (rem & 7) * 128;            // out-dim tile

  const unsigned short* A  = Pb  + (size_t)b * TT * TT + (size_t)row0 * TT;
  const unsigned short* Bm = vtb + (size_t)b * DD * TT + (size_t)col0 * TT;

  f32x4 acc[4][4];
  #pragma unroll
  for (int m = 0; m < 4; ++m)
    #pragma unroll
    for (int n = 0; n < 4; ++n)
      acc[m][n] = (f32x4){0.f, 0.f, 0.f, 0.f};

  gemm_core(A, Bm, TT, TT, 0, row0 + 128, smem, acc);

  const int t = threadIdx.x, w = t >> 6, l = t & 63;
  const int wr = (w >> 1) * 64, wc = (w & 1) * 64;
  #pragma unroll
  for (int m = 0; m < 4; ++m)
    #pragma unroll
    for (int n = 0; n < 4; ++n)
      #pragma unroll
      for (int r = 0; r < 4; ++r) {
        int grow = row0 + wr + m * 16 + (l >> 4) * 4 + r;
        int gcol = col0 + wc + n * 16 + (l & 15);
        out[((size_t)b * TT + grow) * DD + gcol] = acc[m][n][r];
      }
}

// ---------------- launch ----------------
extern "C" void kernel_launch(void* const* d_in, const int* in_sizes, int n_in,
                              void* d_out, int out_size, void* d_ws, size_t ws_size,
                              hipStream_t stream) {
  const float* x  = (const float*)d_in[0];
  const float* Wq = (const float*)d_in[1];
  const float* Wk = (const float*)d_in[2];
  const float* Wv = (const float*)d_in[3];
  float* out = (float*)d_out;

  unsigned short* ws  = (unsigned short*)d_ws;
  unsigned short* xb  = ws;                        // 8192*1024
  unsigned short* wqb = xb  + (size_t)MTOT * DD;   // 1024*1024
  unsigned short* wkb = wqb + (size_t)DD * DD;
  unsigned short* wvb = wkb + (size_t)DD * DD;
  unsigned short* qb  = wvb + (size_t)DD * DD;     // 8192*1024
  unsigned short* kb  = qb  + (size_t)MTOT * DD;   // 8192*1024
  unsigned short* vtb = kb  + (size_t)MTOT * DD;   // 4*1024*2048 (vT)
  unsigned short* Pb  = vtb + (size_t)MTOT * DD;   // 4*2048*2048

  {
    const int NX = (MTOT * DD) / 4, NW = (DD * DD) / 4;
    const int ntot = NX + 3 * NW;
    cvt_all<<<(ntot + 255) / 256, 256, 0, stream>>>(x, Wq, Wk, Wv, xb, wqb, wkb, wvb);
  }

  qkv_gemm256<<<dim3(384), 512, 0, stream>>>(xb, wqb, wkb, wvb, qb, kb, vtb);

  qk_gemm<<<dim3(544), 256, 0, stream>>>(qb, kb, Pb);

  softmax_kernel<<<dim3(TT, NB), 256, 0, stream>>>(Pb);

  pv_gemm<<<dim3(512), 256, 0, stream>>>(Pb, vtb, out);
}